// Round 3
// baseline (164.741 us; speedup 1.0000x reference)
//
#include <hip/hip_runtime.h>
#include <math.h>

// EfficientGCN preprocess:
//   x: (N=128, C=3, T=300, V=25, M=2) fp32, out: (N, 3, 2C=6, T, V, M) fp32
// One thread handles 4 consecutive (t,v,m) flat positions ("a quad") for all
// 18 output planes: 16B/lane aligned float4 stores, nontemporal (write-once).
// Gathers (center joint v=1, parent joint) are scalar loads served by L1.

typedef float vfloat4 __attribute__((ext_vector_type(4)));   // clang vector: OK for nontemporal builtin
typedef float vfloat2 __attribute__((ext_vector_type(2)));

constexpr int PLANE = 15000;          // floats per (n,c) plane: T*V*M = 300*50
constexpr int QPN   = PLANE / 4;      // 3750 quads per plane
constexpr int NQ    = 128 * QPN;      // 480000 threads total (= 1875 * 256)

__global__ __launch_bounds__(256)
void egcn_pre_kernel(const float* __restrict__ x,
                     const int* __restrict__ conn,
                     float* __restrict__ out) {
    int q = blockIdx.x * blockDim.x + threadIdx.x;
    int n = q / QPN;
    int f = (q - n * QPN) << 2;       // flat (t,v,m) base, multiple of 4

    // Per-element coordinates. A quad spans at most 2 t-rows (50 floats/row).
    int idxc[4], idxp[4];
    float vmask[4];
#pragma unroll
    for (int i = 0; i < 4; ++i) {
        int e  = f + i;
        int ti = e / 50;
        int vm = e - ti * 50;
        int mi = vm & 1;
        idxc[i]  = ti * 50 + 2 + mi;                      // center joint v=1
        idxp[i]  = ti * 50 + (conn[vm >> 1] << 1) + mi;   // parent joint
        vmask[i] = (ti < 298) ? 1.0f : 0.0f;
    }
    // If the first row >= 298, no element needs velocity; also keeps the
    // f+50/f+100 loads in-bounds (max needed f = 14896 -> f+103 = 14999).
    const bool anyvel = (f < 14900);

    const float* xn = x + (size_t)n * (3 * PLANE);
    float xv[3][4], x1[3][4], x2[3][4], xc[3][4], xp[3][4];
#pragma unroll
    for (int c = 0; c < 3; ++c) {
        const float* pl = xn + c * PLANE;
        *reinterpret_cast<vfloat4*>(xv[c]) = *reinterpret_cast<const vfloat4*>(pl + f);
        if (anyvel) {   // f+50 is only 8B-aligned: two float2 loads
            *reinterpret_cast<vfloat2*>(&x1[c][0]) = *reinterpret_cast<const vfloat2*>(pl + f + 50);
            *reinterpret_cast<vfloat2*>(&x1[c][2]) = *reinterpret_cast<const vfloat2*>(pl + f + 52);
            *reinterpret_cast<vfloat2*>(&x2[c][0]) = *reinterpret_cast<const vfloat2*>(pl + f + 100);
            *reinterpret_cast<vfloat2*>(&x2[c][2]) = *reinterpret_cast<const vfloat2*>(pl + f + 102);
        } else {
#pragma unroll
            for (int i = 0; i < 4; ++i) { x1[c][i] = 0.f; x2[c][i] = 0.f; }
        }
#pragma unroll
        for (int i = 0; i < 4; ++i) {
            xc[c][i] = pl[idxc[i]];
            xp[c][i] = pl[idxp[i]];
        }
    }

    // Bone length per element (reduce over c), strictly |bv|/len < 1 so acosf safe.
    float inv[4];
#pragma unroll
    for (int i = 0; i < 4; ++i) {
        float b0 = xv[0][i] - xp[0][i];
        float b1 = xv[1][i] - xp[1][i];
        float b2 = xv[2][i] - xp[2][i];
        inv[i] = 1.0f / (sqrtf(b0 * b0 + b1 * b1 + b2 * b2) + 1e-4f);
    }

    float* outn = out + (size_t)n * (18 * PLANE);
    auto st = [&](int plane, float a, float b, float c2, float d) {
        vfloat4 val = {a, b, c2, d};
        __builtin_nontemporal_store(val,
            reinterpret_cast<vfloat4*>(outn + plane * PLANE + f));
    };

#pragma unroll
    for (int c = 0; c < 3; ++c) {
        // branch 0: joint = [x ; x - x_center]
        st(c,     xv[c][0], xv[c][1], xv[c][2], xv[c][3]);
        st(c + 3, xv[c][0] - xc[c][0], xv[c][1] - xc[c][1],
                  xv[c][2] - xc[c][2], xv[c][3] - xc[c][3]);
        // branch 1: velocity = [x(t+1)-x(t) ; x(t+2)-x(t)], zero for t>=298
        st(c + 6, (x1[c][0] - xv[c][0]) * vmask[0], (x1[c][1] - xv[c][1]) * vmask[1],
                  (x1[c][2] - xv[c][2]) * vmask[2], (x1[c][3] - xv[c][3]) * vmask[3]);
        st(c + 9, (x2[c][0] - xv[c][0]) * vmask[0], (x2[c][1] - xv[c][1]) * vmask[1],
                  (x2[c][2] - xv[c][2]) * vmask[2], (x2[c][3] - xv[c][3]) * vmask[3]);
        // branch 2: bone = [bv ; acos(bv / (||bv|| + 1e-4))]
        float bv[4], ang[4];
#pragma unroll
        for (int i = 0; i < 4; ++i) {
            bv[i]  = xv[c][i] - xp[c][i];
            ang[i] = acosf(bv[i] * inv[i]);
        }
        st(c + 12, bv[0], bv[1], bv[2], bv[3]);
        st(c + 15, ang[0], ang[1], ang[2], ang[3]);
    }
}

extern "C" void kernel_launch(void* const* d_in, const int* in_sizes, int n_in,
                              void* d_out, int out_size, void* d_ws, size_t ws_size,
                              hipStream_t stream) {
    const float* x  = (const float*)d_in[0];
    const int* conn = (const int*)d_in[1];
    float* out      = (float*)d_out;

    int block = 256;
    int grid  = NQ / block;           // 1875, exact
    egcn_pre_kernel<<<grid, block, 0, stream>>>(x, conn, out);
}